// Round 4
// baseline (827.226 us; speedup 1.0000x reference)
//
#include <hip/hip_runtime.h>
#include <hip/hip_bf16.h>
#include <cstdint>
#include <cstddef>

// ---------------- problem constants ----------------
#define TOKENS 16384        // B*S
#define DIM    1024         // D
#define NEXP   8            // E
#define HID    2048         // H
#define PAIRS  32768        // TOKENS*K
#define PADCAP 33792        // max padded pairs (32768 + 8*128, tile-aligned)
#define MTILES 264          // PADCAP/128

typedef short     bf16x8 __attribute__((ext_vector_type(8)));
typedef float     f32x4  __attribute__((ext_vector_type(4)));

// float -> bf16 bits (round-to-nearest-even)
__device__ __forceinline__ unsigned short f2bf(float f) {
  union { float f; uint32_t u; } v; v.f = f;
  uint32_t u = v.u;
  uint32_t r = (u + 0x7FFFu + ((u >> 16) & 1u)) >> 16;
  return (unsigned short)r;
}

__device__ __forceinline__ void gload_lds16(const void* g, void* l) {
  __builtin_amdgcn_global_load_lds(
      (const __attribute__((address_space(1))) unsigned int*)g,
      (__attribute__((address_space(3))) unsigned int*)l,
      16, 0, 0);
}

// src: [E][R][C] f32 row-major  ->  dst: [E][C][R] bf16 (transposed per expert)
__global__ __launch_bounds__(256) void tcvt(const float* __restrict__ src,
                                            unsigned short* __restrict__ dst,
                                            int R, int C) {
  __shared__ unsigned short t[64][72];
  const float* s = src + (size_t)blockIdx.z * R * C;
  unsigned short* d = dst + (size_t)blockIdx.z * R * C;
  int r0 = blockIdx.y * 64, c0 = blockIdx.x * 64;
  int tr = threadIdx.x >> 4;      // 0..15
  int tc = threadIdx.x & 15;      // 0..15
#pragma unroll
  for (int i = 0; i < 4; ++i) {
    int r = tr + i * 16;
    float4 v = *(const float4*)&s[(size_t)(r0 + r) * C + c0 + tc * 4];
    t[r][tc * 4 + 0] = f2bf(v.x);
    t[r][tc * 4 + 1] = f2bf(v.y);
    t[r][tc * 4 + 2] = f2bf(v.z);
    t[r][tc * 4 + 3] = f2bf(v.w);
  }
  __syncthreads();
#pragma unroll
  for (int i = 0; i < 4; ++i) {
    int c = tr + i * 16;
    ushort4 o;
    o.x = t[tc * 4 + 0][c];
    o.y = t[tc * 4 + 1][c];
    o.z = t[tc * 4 + 2][c];
    o.w = t[tc * 4 + 3][c];
    *(ushort4*)&d[(size_t)(c0 + c) * R + r0 + tc * 4] = o;
  }
}

// ---------------- router (fp32 exact) + fused hs->bf16 conversion ----------------
__global__ __launch_bounds__(256) void router(const float* __restrict__ hs,
                                              const float* __restrict__ Wr,
                                              const float* __restrict__ br,
                                              unsigned short* __restrict__ Xb,
                                              int2* __restrict__ tok_e,
                                              float2* __restrict__ tok_w,
                                              int* __restrict__ counts) {
  __shared__ float wrT[NEXP][1032];   // [E][D] padded: f32x4 reads are <=2-way conflict (free)
  __shared__ int hist[NEXP];
  int tid = threadIdx.x;
  if (tid < NEXP) hist[tid] = 0;
#pragma unroll
  for (int j = 0; j < 4; ++j) {
    int d = tid * 4 + j;
    float4 lo = *(const float4*)&Wr[d * 8];
    float4 hi = *(const float4*)&Wr[d * 8 + 4];
    wrT[0][d] = lo.x; wrT[1][d] = lo.y; wrT[2][d] = lo.z; wrT[3][d] = lo.w;
    wrT[4][d] = hi.x; wrT[5][d] = hi.y; wrT[6][d] = hi.z; wrT[7][d] = hi.w;
  }
  __syncthreads();
  int wave = tid >> 6, lane = tid & 63;

  for (int i = 0; i < 4; ++i) {
    int t = blockIdx.x * 16 + wave * 4 + i;
    float4 x[4];
#pragma unroll
    for (int p = 0; p < 4; ++p) {
      int d = p * 256 + lane * 4;
      x[p] = *(const float4*)&hs[(size_t)t * DIM + d];
      ushort4 o;
      o.x = f2bf(x[p].x); o.y = f2bf(x[p].y); o.z = f2bf(x[p].z); o.w = f2bf(x[p].w);
      *(ushort4*)&Xb[(size_t)t * DIM + d] = o;
    }
    float acc[NEXP];
#pragma unroll
    for (int e = 0; e < NEXP; ++e) {
      float a = 0.f;
#pragma unroll
      for (int p = 0; p < 4; ++p) {
        float4 w4 = *(const float4*)&wrT[e][p * 256 + lane * 4];
        a += x[p].x * w4.x + x[p].y * w4.y + x[p].z * w4.z + x[p].w * w4.w;
      }
      acc[e] = a;
    }
#pragma unroll
    for (int e = 0; e < NEXP; ++e) {
#pragma unroll
      for (int off = 32; off; off >>= 1) acc[e] += __shfl_xor(acc[e], off);
    }
    if (lane == 0) {
      float l[NEXP];
#pragma unroll
      for (int e = 0; e < NEXP; ++e) l[e] = acc[e] + br[e];
      float m = l[0];
#pragma unroll
      for (int e = 1; e < NEXP; ++e) m = fmaxf(m, l[e]);
      float p[NEXP], s = 0.f;
#pragma unroll
      for (int e = 0; e < NEXP; ++e) { p[e] = expf(l[e] - m); s += p[e]; }
      // top-2 on probabilities; strict > keeps lowest index on ties (jax.lax.top_k)
      int e0 = 0;
#pragma unroll
      for (int e = 1; e < NEXP; ++e) if (p[e] > p[e0]) e0 = e;
      int e1 = (e0 == 0) ? 1 : 0;
#pragma unroll
      for (int e = 0; e < NEXP; ++e) if (e != e0 && p[e] > p[e1]) e1 = e;
      float q0 = p[e0] / s, q1 = p[e1] / s;
      float den = q0 + q1 + 1e-8f;
      tok_e[t] = make_int2(e0, e1);
      tok_w[t] = make_float2(q0 / den, q1 / den);
      atomicAdd(&hist[e0], 1);
      atomicAdd(&hist[e1], 1);
    }
  }
  __syncthreads();
  if (tid < NEXP)
    atomicAdd(&counts[(tid * 8 + (blockIdx.x & 7)) * 32], hist[tid]);
}

// counts[(e*8+p)*32] summed; offs[e] = 128-aligned running offset
__global__ void mk_offsets(const int* __restrict__ counts, int* __restrict__ offs) {
  __shared__ int tot[NEXP];
  int e = threadIdx.x;
  if (e < NEXP) {
    int c = 0;
#pragma unroll
    for (int p = 0; p < 8; ++p) c += counts[(e * 8 + p) * 32];
    tot[e] = c;
  }
  __syncthreads();
  if (threadIdx.x == 0) {
    int o = 0;
#pragma unroll
    for (int i = 0; i < NEXP; ++i) {
      offs[i] = o;
      o += (tot[i] + 127) & ~127;
    }
    offs[NEXP] = o;
  }
}

// 64 blocks x 256 tokens: LDS-atomic within-block rank + 1 global atomic per
// (expert,block) on padded lines.
__global__ __launch_bounds__(256) void scatter(const int2* __restrict__ tok_e,
                                               const float2* __restrict__ tok_w,
                                               const int* __restrict__ offs,
                                               int* __restrict__ gfill,
                                               int* __restrict__ ptok,
                                               float* __restrict__ pw) {
  __shared__ int lfill[NEXP], lbase[NEXP];
  int tid = threadIdx.x;
  if (tid < NEXP) lfill[tid] = 0;
  __syncthreads();
  int t = blockIdx.x * 256 + tid;
  int2 e = tok_e[t];
  float2 w = tok_w[t];
  int r0 = atomicAdd(&lfill[e.x], 1);
  int r1 = atomicAdd(&lfill[e.y], 1);
  __syncthreads();
  if (tid < NEXP) lbase[tid] = atomicAdd(&gfill[tid * 32], lfill[tid]);
  __syncthreads();
  int p0 = offs[e.x] + lbase[e.x] + r0;
  ptok[p0] = t; pw[p0] = w.x;
  int p1 = offs[e.y] + lbase[e.y] + r1;
  ptok[p1] = t; pw[p1] = w.y;
}

// ---------------- grouped GEMM (128x128 tile, BK=64, 4 waves, LDS dbuf) ----------------
// grid: x = N-tile (fast axis, A-tile reuse in L2), y = M-tile (expert segments)
// MODE 0: Abuf[row][n] = gelu( gather(Xb)[row] @ W1bT[e][n][:] + b1[e][n] )   (bf16 out)
// MODE 1: Out[tok[row]][n] += w[row] * ( Abuf[row] @ W2bT[e][n][:] + b2[e][n] ) (f32 atomic)
template <int MODE>
__global__ __launch_bounds__(256) void gemm_moe(
    const unsigned short* __restrict__ Asrc,
    const unsigned short* __restrict__ Bsrc,   // [E][Ntot][Ktot] bf16 (K-contig rows)
    const float* __restrict__ bias,            // [E][Ntot]
    const int* __restrict__ offs,              // [9]
    const int* __restrict__ ptok,
    const float* __restrict__ pw,
    unsigned short* __restrict__ Abuf,
    float* __restrict__ Out,
    int Ktot, int Ntot) {
  int row0 = blockIdx.y * 128;
  int padded_total = offs[NEXP];
  if (row0 >= padded_total) return;
  int e = 0;
  while (e < NEXP - 1 && row0 >= offs[e + 1]) ++e;
  int col0 = blockIdx.x * 128;

  __shared__ unsigned short As[2][128 * 64];   // double-buffered (T3-minimum)
  __shared__ unsigned short Bs[2][128 * 64];
  __shared__ int   sTok[128];
  __shared__ float sW[128];

  int tid = threadIdx.x, wave = tid >> 6, lane = tid & 63;

  if (MODE == 1 && tid < 128) {
    sTok[tid] = ptok[row0 + tid];
    sW[tid]   = pw[row0 + tid];
  }

  // staging: each wave stages rows [wave*32, wave*32+32), 4 issues x 8 rows;
  // lane covers 16B at pre-swizzled source column so the linear global_load_lds
  // write leaves LDS XOR-swizzled (rule #21).
  int swz_src = (((lane & 7) ^ ((lane >> 3) & 7)) << 4);
  const char* aBase[4];
  const char* bBase[4];
#pragma unroll
  for (int i = 0; i < 4; ++i) {
    int r = wave * 32 + i * 8 + (lane >> 3);
    long arow;
    if (MODE == 0) arow = ptok[row0 + r];
    else           arow = row0 + r;
    aBase[i] = (const char*)Asrc + (size_t)arow * Ktot * 2 + swz_src;
    bBase[i] = (const char*)Bsrc + ((size_t)e * Ntot + col0 + r) * Ktot * 2 + swz_src;
  }

  f32x4 acc[4][4] = {};

  int wm = wave >> 1, wn = wave & 1;
  int rsel = lane & 15;
  int kblk = (lane >> 4) * 16;       // byte offset of this lane's k-slice
  int rswz = (lane & 7) << 4;        // read-side XOR: (row&7)<<4 == (lane&7)<<4

  // prologue: stage K-tile 0 into buf 0, drain, barrier
#pragma unroll
  for (int i = 0; i < 4; ++i) {
    gload_lds16(aBase[i], &As[0][(wave * 32 + i * 8) * 64]);
    gload_lds16(bBase[i], &Bs[0][(wave * 32 + i * 8) * 64]);
  }
  __syncthreads();   // compiler emits vmcnt(0) before s_barrier -> tile 0 landed

  int cur = 0;
  for (int kt = 0; kt < Ktot; kt += 64, cur ^= 1) {
    // 1) issue next tile's loads FIRST (fly during MFMA, drain at the barrier)
    if (kt + 64 < Ktot) {
      int nxt = cur ^ 1;
#pragma unroll
      for (int i = 0; i < 4; ++i) {
        gload_lds16(aBase[i] + (kt + 64) * 2, &As[nxt][(wave * 32 + i * 8) * 64]);
        gload_lds16(bBase[i] + (kt + 64) * 2, &Bs[nxt][(wave * 32 + i * 8) * 64]);
      }
    }
    // 2) compute current tile from LDS
#pragma unroll
    for (int kk = 0; kk < 2; ++kk) {
      bf16x8 af[4], bfr[4];
#pragma unroll
      for (int i = 0; i < 4; ++i) {
        int row = wm * 64 + i * 16 + rsel;
        af[i] = *(const bf16x8*)((const char*)As[cur] + row * 128 + ((kk * 64 + kblk) ^ rswz));
      }
#pragma unroll
      for (int j = 0; j < 4; ++j) {
        int row = wn * 64 + j * 16 + rsel;
        bfr[j] = *(const bf16x8*)((const char*)Bs[cur] + row * 128 + ((kk * 64 + kblk) ^ rswz));
      }
#pragma unroll
      for (int i = 0; i < 4; ++i)
#pragma unroll
        for (int j = 0; j < 4; ++j)
          acc[i][j] = __builtin_amdgcn_mfma_f32_16x16x32_bf16(af[i], bfr[j], acc[i][j], 0, 0, 0);
    }
    // 3) single barrier per K-step: drains next-tile loads AND guards buffer reuse
    __syncthreads();
  }

  // epilogue: C/D layout col = lane&15, row = (lane>>4)*4 + r  [m89-verified]
  int crow = (lane >> 4) * 4;
  int ccol = lane & 15;
#pragma unroll
  for (int i = 0; i < 4; ++i) {
#pragma unroll
    for (int j = 0; j < 4; ++j) {
      int gcol = col0 + wn * 64 + j * 16 + ccol;
      float bv = bias[(size_t)e * Ntot + gcol];
#pragma unroll
      for (int r = 0; r < 4; ++r) {
        int lrow = wm * 64 + i * 16 + crow + r;
        float v = acc[i][j][r] + bv;
        if (MODE == 0) {
          float g = 0.5f * v * (1.0f + erff(v * 0.70710678118654752f));
          Abuf[(size_t)(row0 + lrow) * HID + gcol] = f2bf(g);
        } else {
          atomicAdd(&Out[(size_t)sTok[lrow] * DIM + gcol], sW[lrow] * v);
        }
      }
    }
  }
}

// ---------------- launch ----------------
extern "C" void kernel_launch(void* const* d_in, const int* in_sizes, int n_in,
                              void* d_out, int out_size, void* d_ws, size_t ws_size,
                              hipStream_t stream) {
  const float* hs = (const float*)d_in[0];
  const float* Wr = (const float*)d_in[1];
  const float* br = (const float*)d_in[2];
  const float* W1 = (const float*)d_in[3];
  const float* b1 = (const float*)d_in[4];
  const float* W2 = (const float*)d_in[5];
  const float* b2 = (const float*)d_in[6];
  float* out = (float*)d_out;

  char* ws = (char*)d_ws;
  unsigned short* W1bT = (unsigned short*)(ws);                    // 32 MB  [E][H][D]
  unsigned short* W2bT = (unsigned short*)(ws + 33554432);         // 32 MB  [E][D][H]
  unsigned short* Xb   = (unsigned short*)(ws + 67108864);         // 32 MB  [T][D]
  unsigned short* Abuf = (unsigned short*)(ws + 100663296);        // 132 MB [PADCAP][H]
  char* rb = ws + 239075328;
  int*    counts = (int*)(rb);                     // 64 lines x 128B = 8192 B
  int*    gfill  = (int*)(rb + 8192);              // 8 lines x 128B = 1024 B
  int*    offs   = (int*)(rb + 9216);              // 9 ints (padded to 128)
  int2*   tok_e  = (int2*)(rb + 9344);             // 131072 B
  float2* tok_w  = (float2*)(rb + 140416);         // 131072 B
  int*    ptok   = (int*)(rb + 271488);            // 135168 B
  float*  pw     = (float*)(rb + 406656);          // 135168 B
  size_t routing_bytes = 541824;

  hipMemsetAsync(rb, 0, routing_bytes, stream);
  hipMemsetAsync(out, 0, (size_t)out_size * sizeof(float), stream);

  dim3 t1g(HID / 64, DIM / 64, NEXP);
  tcvt<<<t1g, 256, 0, stream>>>(W1, W1bT, DIM, HID);   // [D][H] -> [H][D]
  dim3 t2g(DIM / 64, HID / 64, NEXP);
  tcvt<<<t2g, 256, 0, stream>>>(W2, W2bT, HID, DIM);   // [H][D] -> [D][H]

  router<<<1024, 256, 0, stream>>>(hs, Wr, br, Xb, tok_e, tok_w, counts);
  mk_offsets<<<1, 64, 0, stream>>>(counts, offs);
  scatter<<<TOKENS / 256, 256, 0, stream>>>(tok_e, tok_w, offs, gfill, ptok, pw);

  dim3 g1(HID / 128, MTILES);   // 16 x 264  (N-tile fast -> A-tile L2 reuse)
  gemm_moe<0><<<g1, 256, 0, stream>>>(Xb, W1bT, b1, offs, ptok, pw, Abuf, out, DIM, HID);
  dim3 g2(DIM / 128, MTILES);   // 8 x 264
  gemm_moe<1><<<g2, 256, 0, stream>>>(Abuf, W2bT, b2, offs, ptok, pw, Abuf, out, HID, DIM);
}

// Round 5
// 775.744 us; speedup vs baseline: 1.0664x; 1.0664x over previous
//
#include <hip/hip_runtime.h>
#include <hip/hip_bf16.h>
#include <cstdint>
#include <cstddef>

// ---------------- problem constants ----------------
#define TOKENS 16384        // B*S
#define DIM    1024         // D
#define NEXP   8            // E
#define HID    2048         // H
#define PAIRS  32768        // TOKENS*K
#define PADCAP 34816        // 32768 + 8*256 (segments padded to 256)
#define MT256  136          // PADCAP/256

typedef short     bf16x8 __attribute__((ext_vector_type(8)));
typedef float     f32x4  __attribute__((ext_vector_type(4)));

// float -> bf16 bits (round-to-nearest-even)
__device__ __forceinline__ unsigned short f2bf(float f) {
  union { float f; uint32_t u; } v; v.f = f;
  uint32_t u = v.u;
  uint32_t r = (u + 0x7FFFu + ((u >> 16) & 1u)) >> 16;
  return (unsigned short)r;
}

// exact GELU via Abramowitz-Stegun 7.1.26 erf (abs err 1.5e-7, ~12 VALU ops
// vs libm erff's ~40+) — replaces the expensive epilogue erff.
__device__ __forceinline__ float gelu_f(float v) {
  float x = v * 0.70710678118654752f;
  float ax = fabsf(x);
  float t = __builtin_amdgcn_rcpf(1.0f + 0.3275911f * ax);
  float p = t * (0.254829592f +
           t * (-0.284496736f +
           t * (1.421413741f +
           t * (-1.453152027f +
           t * 1.061405429f))));
  float erfv = 1.0f - p * __expf(-ax * ax);
  erfv = (x < 0.f) ? -erfv : erfv;
  return 0.5f * v * (1.0f + erfv);
}

__device__ __forceinline__ void gload_lds16(const void* g, void* l) {
  __builtin_amdgcn_global_load_lds(
      (const __attribute__((address_space(1))) unsigned int*)g,
      (__attribute__((address_space(3))) unsigned int*)l,
      16, 0, 0);
}

// src: [E][R][C] f32 row-major  ->  dst: [E][C][R] bf16 (transposed per expert)
__global__ __launch_bounds__(256) void tcvt(const float* __restrict__ src,
                                            unsigned short* __restrict__ dst,
                                            int R, int C) {
  __shared__ unsigned short t[64][72];
  const float* s = src + (size_t)blockIdx.z * R * C;
  unsigned short* d = dst + (size_t)blockIdx.z * R * C;
  int r0 = blockIdx.y * 64, c0 = blockIdx.x * 64;
  int tr = threadIdx.x >> 4;      // 0..15
  int tc = threadIdx.x & 15;      // 0..15
#pragma unroll
  for (int i = 0; i < 4; ++i) {
    int r = tr + i * 16;
    float4 v = *(const float4*)&s[(size_t)(r0 + r) * C + c0 + tc * 4];
    t[r][tc * 4 + 0] = f2bf(v.x);
    t[r][tc * 4 + 1] = f2bf(v.y);
    t[r][tc * 4 + 2] = f2bf(v.z);
    t[r][tc * 4 + 3] = f2bf(v.w);
  }
  __syncthreads();
#pragma unroll
  for (int i = 0; i < 4; ++i) {
    int c = tr + i * 16;
    ushort4 o;
    o.x = t[tc * 4 + 0][c];
    o.y = t[tc * 4 + 1][c];
    o.z = t[tc * 4 + 2][c];
    o.w = t[tc * 4 + 3][c];
    *(ushort4*)&d[(size_t)(c0 + c) * R + r0 + tc * 4] = o;
  }
}

// ---------------- router (fp32 exact) + fused hs->bf16 conversion ----------------
__global__ __launch_bounds__(256) void router(const float* __restrict__ hs,
                                              const float* __restrict__ Wr,
                                              const float* __restrict__ br,
                                              unsigned short* __restrict__ Xb,
                                              int2* __restrict__ tok_e,
                                              float2* __restrict__ tok_w,
                                              int* __restrict__ counts) {
  __shared__ float wrT[NEXP][1032];   // [E][D] padded: f32x4 reads are <=2-way conflict (free)
  __shared__ int hist[NEXP];
  int tid = threadIdx.x;
  if (tid < NEXP) hist[tid] = 0;
#pragma unroll
  for (int j = 0; j < 4; ++j) {
    int d = tid * 4 + j;
    float4 lo = *(const float4*)&Wr[d * 8];
    float4 hi = *(const float4*)&Wr[d * 8 + 4];
    wrT[0][d] = lo.x; wrT[1][d] = lo.y; wrT[2][d] = lo.z; wrT[3][d] = lo.w;
    wrT[4][d] = hi.x; wrT[5][d] = hi.y; wrT[6][d] = hi.z; wrT[7][d] = hi.w;
  }
  __syncthreads();
  int wave = tid >> 6, lane = tid & 63;

  for (int i = 0; i < 4; ++i) {
    int t = blockIdx.x * 16 + wave * 4 + i;
    float4 x[4];
#pragma unroll
    for (int p = 0; p < 4; ++p) {
      int d = p * 256 + lane * 4;
      x[p] = *(const float4*)&hs[(size_t)t * DIM + d];
      ushort4 o;
      o.x = f2bf(x[p].x); o.y = f2bf(x[p].y); o.z = f2bf(x[p].z); o.w = f2bf(x[p].w);
      *(ushort4*)&Xb[(size_t)t * DIM + d] = o;
    }
    float acc[NEXP];
#pragma unroll
    for (int e = 0; e < NEXP; ++e) {
      float a = 0.f;
#pragma unroll
      for (int p = 0; p < 4; ++p) {
        float4 w4 = *(const float4*)&wrT[e][p * 256 + lane * 4];
        a += x[p].x * w4.x + x[p].y * w4.y + x[p].z * w4.z + x[p].w * w4.w;
      }
      acc[e] = a;
    }
#pragma unroll
    for (int e = 0; e < NEXP; ++e) {
#pragma unroll
      for (int off = 32; off; off >>= 1) acc[e] += __shfl_xor(acc[e], off);
    }
    if (lane == 0) {
      float l[NEXP];
#pragma unroll
      for (int e = 0; e < NEXP; ++e) l[e] = acc[e] + br[e];
      float m = l[0];
#pragma unroll
      for (int e = 1; e < NEXP; ++e) m = fmaxf(m, l[e]);
      float p[NEXP], s = 0.f;
#pragma unroll
      for (int e = 0; e < NEXP; ++e) { p[e] = expf(l[e] - m); s += p[e]; }
      // top-2 on probabilities; strict > keeps lowest index on ties (jax.lax.top_k)
      int e0 = 0;
#pragma unroll
      for (int e = 1; e < NEXP; ++e) if (p[e] > p[e0]) e0 = e;
      int e1 = (e0 == 0) ? 1 : 0;
#pragma unroll
      for (int e = 0; e < NEXP; ++e) if (e != e0 && p[e] > p[e1]) e1 = e;
      float q0 = p[e0] / s, q1 = p[e1] / s;
      float den = q0 + q1 + 1e-8f;
      tok_e[t] = make_int2(e0, e1);
      tok_w[t] = make_float2(q0 / den, q1 / den);
      atomicAdd(&hist[e0], 1);
      atomicAdd(&hist[e1], 1);
    }
  }
  __syncthreads();
  if (tid < NEXP)
    atomicAdd(&counts[(tid * 8 + (blockIdx.x & 7)) * 32], hist[tid]);
}

// counts[(e*8+p)*32] summed; offs[e] = 256-aligned running offset
__global__ void mk_offsets(const int* __restrict__ counts, int* __restrict__ offs) {
  __shared__ int tot[NEXP];
  int e = threadIdx.x;
  if (e < NEXP) {
    int c = 0;
#pragma unroll
    for (int p = 0; p < 8; ++p) c += counts[(e * 8 + p) * 32];
    tot[e] = c;
  }
  __syncthreads();
  if (threadIdx.x == 0) {
    int o = 0;
#pragma unroll
    for (int i = 0; i < NEXP; ++i) {
      offs[i] = o;
      o += (tot[i] + 255) & ~255;   // 256-row tiles must not cross experts
    }
    offs[NEXP] = o;
  }
}

// 64 blocks x 256 tokens: LDS-atomic within-block rank + 1 global atomic per
// (expert,block) on padded lines.
__global__ __launch_bounds__(256) void scatter(const int2* __restrict__ tok_e,
                                               const float2* __restrict__ tok_w,
                                               const int* __restrict__ offs,
                                               int* __restrict__ gfill,
                                               int* __restrict__ ptok,
                                               float* __restrict__ pw) {
  __shared__ int lfill[NEXP], lbase[NEXP];
  int tid = threadIdx.x;
  if (tid < NEXP) lfill[tid] = 0;
  __syncthreads();
  int t = blockIdx.x * 256 + tid;
  int2 e = tok_e[t];
  float2 w = tok_w[t];
  int r0 = atomicAdd(&lfill[e.x], 1);
  int r1 = atomicAdd(&lfill[e.y], 1);
  __syncthreads();
  if (tid < NEXP) lbase[tid] = atomicAdd(&gfill[tid * 32], lfill[tid]);
  __syncthreads();
  int p0 = offs[e.x] + lbase[e.x] + r0;
  ptok[p0] = t; pw[p0] = w.x;
  int p1 = offs[e.y] + lbase[e.y] + r1;
  ptok[p1] = t; pw[p1] = w.y;
}

// ------- grouped GEMM: 256x256 tile, BK=64, 8 waves (2Mx4N), 2-phase dbuf -------
// T1 chunked-bijective XCD swizzle: each XCD gets a contiguous wgid chunk so an
// M-row's N-sweep stays in one XCD's L2 (fixes the 8x A-tile refetch).
// MODE 0: Abuf[row][n] = gelu( gather(Xb)[row] @ W1bT[e][n][:] + b1[e][n] )   (bf16)
// MODE 1: Out[tok[row]][n] += w[row] * ( Abuf[row] @ W2bT[e][n][:] + b2[e][n] ) (f32 atomic)
template <int MODE>
__global__ __launch_bounds__(512, 2) void gemm_moe(
    const unsigned short* __restrict__ Asrc,
    const unsigned short* __restrict__ Bsrc,   // [E][Ntot][Ktot] bf16 (K-contig rows)
    const float* __restrict__ bias,            // [E][Ntot]
    const int* __restrict__ offs,              // [9]
    const int* __restrict__ ptok,
    const float* __restrict__ pw,
    unsigned short* __restrict__ Abuf,
    float* __restrict__ Out,
    int Ktot, int Ntot) {
  const int nx = Ntot >> 8;                    // N-tiles of 256
  int total = gridDim.x;
  int bid = blockIdx.x;
  int q = total >> 3, r8 = total & 7;
  int xcd = bid & 7, idx = bid >> 3;
  int wgid = (xcd < r8 ? xcd * (q + 1) : r8 * (q + 1) + (xcd - r8) * q) + idx;
  int col0 = (wgid % nx) * 256;
  int row0 = (wgid / nx) * 256;
  if (row0 >= offs[NEXP]) return;
  int e = 0;
  while (e < NEXP - 1 && row0 >= offs[e + 1]) ++e;

  __shared__ unsigned short As[2][256 * 64];   // 64 KB
  __shared__ unsigned short Bs[2][256 * 64];   // 64 KB
  __shared__ int   sTok[256];
  __shared__ float sW[256];

  int tid = threadIdx.x, wave = tid >> 6, lane = tid & 63;

  if (MODE == 1 && tid < 256) {
    sTok[tid] = ptok[row0 + tid];
    sW[tid]   = pw[row0 + tid];
  }

  // staging: wave w covers rows [w*32, w*32+32) of As and Bs, 4 issues x 8 rows;
  // lane reads 16B at the pre-swizzled source column so the linear
  // global_load_lds write leaves LDS XOR-swizzled (rule #21).
  int swz_src = (((lane & 7) ^ ((lane >> 3) & 7)) << 4);
  size_t rowB = (size_t)Ktot * 2;
  const char* aB[4];
  const char* bB0 = (const char*)Bsrc +
      ((size_t)e * Ntot + col0 + wave * 32 + (lane >> 3)) * rowB + swz_src;
#pragma unroll
  for (int i = 0; i < 4; ++i) {
    int rr = wave * 32 + i * 8 + (lane >> 3);
    long arow = (MODE == 0) ? (long)ptok[row0 + rr] : (long)(row0 + rr);
    aB[i] = (const char*)Asrc + (size_t)arow * rowB + swz_src;
  }

  f32x4 acc[8][4] = {};

  int wm = wave >> 2, wn = wave & 3;           // 2M x 4N wave grid
  int rsel = lane & 15;
  int kblk = (lane >> 4) * 16;                 // byte offset of this lane's k-slice
  int rswz = (lane & 7) << 4;                  // read-side XOR: (row&7)<<4 == (lane&7)<<4

  // prologue: stage K-tile 0
#pragma unroll
  for (int i = 0; i < 4; ++i) {
    gload_lds16(aB[i], &As[0][(wave * 32 + i * 8) * 64]);
    gload_lds16(bB0 + (size_t)i * 8 * rowB, &Bs[0][(wave * 32 + i * 8) * 64]);
  }
  __syncthreads();

  int cur = 0;
  for (int kt = 0; kt < Ktot; kt += 64, cur ^= 1) {
    if (kt + 64 < Ktot) {
      int nxt = cur ^ 1;
#pragma unroll
      for (int i = 0; i < 4; ++i) {
        gload_lds16(aB[i] + (kt + 64) * 2, &As[nxt][(wave * 32 + i * 8) * 64]);
        gload_lds16(bB0 + (size_t)i * 8 * rowB + (kt + 64) * 2,
                    &Bs[nxt][(wave * 32 + i * 8) * 64]);
      }
    }
#pragma unroll
    for (int kk = 0; kk < 2; ++kk) {
      bf16x8 af[8], bfr[4];
#pragma unroll
      for (int i = 0; i < 8; ++i) {
        int row = wm * 128 + i * 16 + rsel;
        af[i] = *(const bf16x8*)((const char*)As[cur] + row * 128 + ((kk * 64 + kblk) ^ rswz));
      }
#pragma unroll
      for (int j = 0; j < 4; ++j) {
        int row = wn * 64 + j * 16 + rsel;
        bfr[j] = *(const bf16x8*)((const char*)Bs[cur] + row * 128 + ((kk * 64 + kblk) ^ rswz));
      }
#pragma unroll
      for (int i = 0; i < 8; ++i)
#pragma unroll
        for (int j = 0; j < 4; ++j)
          acc[i][j] = __builtin_amdgcn_mfma_f32_16x16x32_bf16(af[i], bfr[j], acc[i][j], 0, 0, 0);
    }
    __syncthreads();
  }

  // epilogue: C/D layout col = lane&15, row = (lane>>4)*4 + r  [m89-verified]
  int crow = (lane >> 4) * 4;
  int ccol = lane & 15;
#pragma unroll
  for (int i = 0; i < 8; ++i) {
#pragma unroll
    for (int j = 0; j < 4; ++j) {
      int gcol = col0 + wn * 64 + j * 16 + ccol;
      float bv = bias[(size_t)e * Ntot + gcol];
#pragma unroll
      for (int r = 0; r < 4; ++r) {
        int lrow = wm * 128 + i * 16 + crow + r;
        float v = acc[i][j][r] + bv;
        if (MODE == 0) {
          Abuf[(size_t)(row0 + lrow) * HID + gcol] = f2bf(gelu_f(v));
        } else {
          atomicAdd(&Out[(size_t)sTok[lrow] * DIM + gcol], sW[lrow] * v);
        }
      }
    }
  }
}

// ---------------- launch ----------------
extern "C" void kernel_launch(void* const* d_in, const int* in_sizes, int n_in,
                              void* d_out, int out_size, void* d_ws, size_t ws_size,
                              hipStream_t stream) {
  const float* hs = (const float*)d_in[0];
  const float* Wr = (const float*)d_in[1];
  const float* br = (const float*)d_in[2];
  const float* W1 = (const float*)d_in[3];
  const float* b1 = (const float*)d_in[4];
  const float* W2 = (const float*)d_in[5];
  const float* b2 = (const float*)d_in[6];
  float* out = (float*)d_out;

  char* ws = (char*)d_ws;
  unsigned short* W1bT = (unsigned short*)(ws);                    // 32 MB  [E][H][D]
  unsigned short* W2bT = (unsigned short*)(ws + 33554432);         // 32 MB  [E][D][H]
  unsigned short* Xb   = (unsigned short*)(ws + 67108864);         // 32 MB  [T][D]
  unsigned short* Abuf = (unsigned short*)(ws + 100663296);        // 136 MB [PADCAP][H]
  char* rb = ws + 100663296 + (size_t)PADCAP * HID * 2;            // 243269632
  int*    counts = (int*)(rb);                     // 64 lines x 128B = 8192 B
  int*    gfill  = (int*)(rb + 8192);              // 8 lines x 128B = 1024 B
  int*    offs   = (int*)(rb + 9216);              // 9 ints (padded to 128)
  int2*   tok_e  = (int2*)(rb + 9344);             // 131072 B
  float2* tok_w  = (float2*)(rb + 140416);         // 131072 B
  int*    ptok   = (int*)(rb + 271488);            // 139264 B (PADCAP ints)
  float*  pw     = (float*)(rb + 410752);          // 139264 B
  size_t routing_bytes = 550016;

  hipMemsetAsync(rb, 0, routing_bytes, stream);
  hipMemsetAsync(out, 0, (size_t)out_size * sizeof(float), stream);

  dim3 t1g(HID / 64, DIM / 64, NEXP);
  tcvt<<<t1g, 256, 0, stream>>>(W1, W1bT, DIM, HID);   // [D][H] -> [H][D]
  dim3 t2g(DIM / 64, HID / 64, NEXP);
  tcvt<<<t2g, 256, 0, stream>>>(W2, W2bT, HID, DIM);   // [H][D] -> [D][H]

  router<<<1024, 256, 0, stream>>>(hs, Wr, br, Xb, tok_e, tok_w, counts);
  mk_offsets<<<1, 64, 0, stream>>>(counts, offs);
  scatter<<<TOKENS / 256, 256, 0, stream>>>(tok_e, tok_w, offs, gfill, ptok, pw);

  // 1-D grids; kernel decodes via chunked XCD swizzle (x=N fast within chunk)
  gemm_moe<0><<<(HID / 256) * MT256, 512, 0, stream>>>(Xb, W1bT, b1, offs, ptok, pw,
                                                       Abuf, out, DIM, HID);
  gemm_moe<1><<<(DIM / 256) * MT256, 512, 0, stream>>>(Abuf, W2bT, b2, offs, ptok, pw,
                                                       Abuf, out, HID, DIM);
}